// Round 10
// baseline (472.450 us; speedup 1.0000x reference)
//
#include <hip/hip_runtime.h>
#include <math.h>

#define EPSF 1e-9f
#define INV_SQRT128 0.08838834764831845f

typedef _Float16 half8 __attribute__((ext_vector_type(8)));
typedef _Float16 half4v __attribute__((ext_vector_type(4)));
typedef float f32x4 __attribute__((ext_vector_type(4)));

// async global->LDS, 16B per lane: lane l reads g[l], HW writes lds_base + l*16
__device__ __forceinline__ void gl_lds16(const void* g, void* l) {
    __builtin_amdgcn_global_load_lds((const __attribute__((address_space(1))) void*)g,
                                     (__attribute__((address_space(3))) void*)l, 16, 0, 0);
}

// ---------------- W pre-pack: fp32 -> (hi fp16, lo fp16*4096) MFMA B-fragments ----------
// R10 layout: slot t = kind*2048 + h*1024 + ks*256 + g*64 + col'  (col = h*64+col').
// Each (kind, head) owns a contiguous 1024-slot (16 KB) segment so k_qkvm can stage
// 32 KB (hi+lo) per phase instead of 64 KB -> 4 blocks/CU instead of 2.
__global__ void k_wpack(const float* __restrict__ Wq, const float* __restrict__ Wk,
                        const float* __restrict__ Wv, half8* __restrict__ whi,
                        half8* __restrict__ wlo, float* __restrict__ w127) {
    int t = blockIdx.x * 256 + threadIdx.x;   // 6144 items
    if (t >= 6144) return;
    int colp = t & 63, g = (t >> 6) & 3, ks = (t >> 8) & 3, h = (t >> 10) & 1, kind = t >> 11;
    int col = h * 64 + colp;
    const float* W = (kind == 0) ? Wq : (kind == 1) ? Wk : Wv;
    const float4* W4 = (const float4*)W;
    float4 a = W4[col * 32 + ks * 8 + g * 2];
    float4 b = W4[col * 32 + ks * 8 + g * 2 + 1];
    float xv[8] = {a.x, a.y, a.z, a.w, b.x, b.y, b.z, b.w};
    half8 hh8, lo;
#pragma unroll
    for (int j = 0; j < 8; j++) {
        _Float16 hh = (_Float16)xv[j];
        hh8[j] = hh;
        lo[j] = (_Float16)((xv[j] - (float)hh) * 4096.0f);
    }
    whi[t] = hh8;
    wlo[t] = lo;
    if (ks == 3 && g == 3) w127[kind * 128 + col] = xv[7];   // W[col][127]
}

// ---------------- Wo pre-pack (for k_outm): slot t=(ks*4+g)*64+col ----------
__global__ void k_wpack2(const float* __restrict__ Wo, half8* __restrict__ wohi,
                         half8* __restrict__ wolo) {
    int t = blockIdx.x * 256 + threadIdx.x;   // 1024 items
    if (t >= 1024) return;
    int col = t & 63, g = (t >> 6) & 3, ks = t >> 8;
    const float4* W4 = (const float4*)Wo;
    float4 a = W4[col * 32 + ks * 8 + g * 2];
    float4 b = W4[col * 32 + ks * 8 + g * 2 + 1];
    float xv[8] = {a.x, a.y, a.z, a.w, b.x, b.y, b.z, b.w};
    half8 h, lo;
#pragma unroll
    for (int j = 0; j < 8; j++) {
        _Float16 hh = (_Float16)xv[j];
        h[j] = hh;
        lo[j] = (_Float16)((xv[j] - (float)hh) * 4096.0f);
    }
    wohi[t] = h;
    wolo[t] = lo;
}

// ---------------- fused qkv via split-fp16 MFMA, B staged in LDS ----------------
// R10: 6 phases of (kind, head); each stages only that head's B = 32 KB LDS total
// (was 64 KB, 2 blocks/CU, 12.5% occupancy, all pipes <20% = latency-bound).
// 32 KB + VGPR 128 + __launch_bounds__(256,4) -> 4 blocks/CU, 4 waves/SIMD.
// Accumulators unchanged (K stays inner), so register footprint stays 128.
// Next-phase staging issued between last ds_read and epilogue (R9 proven pattern).
__global__ void __launch_bounds__(256, 4)
k_qkvm(const float* __restrict__ x,
       const half8* __restrict__ whi, const half8* __restrict__ wlo,
       const float* __restrict__ w127,
       const float* __restrict__ bq, const float* __restrict__ bk,
       const float* __restrict__ bv,
       float* __restrict__ qn, _Float16* __restrict__ knh, float* __restrict__ vn,
       const int* __restrict__ ei, int* __restrict__ bcnt,
       int N, int E, int chunk) {
    int b = (int)blockIdx.x;
    __shared__ half8 bsh[2048];       // 32 KB: [0..1024) hi, [1024..2048) lo
    if (b < 512 && (b & 1)) {         // histogram role (per-chunk coarse counts)
        int* h = (int*)bsh;           // reuse GEMM staging LDS
        int t = threadIdx.x;          // 0..255
        int hid = b >> 1;             // 0..255
        h[t] = 0;
        __syncthreads();
        int s = hid * chunk, e1 = min(s + chunk, E);
        for (int e = s + t; e < e1; e += 256) atomicAdd(&h[ei[e] >> 9], 1);
        __syncthreads();
        bcnt[hid * 256 + t] = h[t];
        return;
    }
    int gb = (b < 512) ? (b >> 1) : (b - 256);   // GEMM block id 0..781

    int tid = threadIdx.x;
    int wv = tid >> 6;                // wave 0..3
    int l = tid & 63;
    int r = l & 15;                   // A-row / out-col lane index
    int g = l >> 4;                   // k-group / out-row group
    int rowbase = gb * 128 + wv * 32;
    const float4* x4 = (const float4*)x;

    // ---- issue phase-0 (kind0, head0) B staging (latency overlaps x processing) ----
    {
        const half8* sH = whi + wv * 256;
        const half8* sL = wlo + wv * 256;
#pragma unroll
        for (int i = 0; i < 4; i++) {
            gl_lds16(sH + i * 64 + l, bsh + wv * 256 + i * 64);
            gl_lds16(sL + i * 64 + l, bsh + 1024 + wv * 256 + i * 64);
        }
    }

    // ---- load x for 2 row-tiles, build hi/lo frags, fold normalization ----
    half8 hiA[2][4], loA[2][4];
    float rnj[2][4], tcj[2][4];
#pragma unroll
    for (int t = 0; t < 2; t++) {
        int row = min(rowbase + t * 16 + r, N - 1);
        float ssum = 0.f, tl = 0.f;
#pragma unroll
        for (int ks = 0; ks < 4; ks++) {
            float4 a = x4[(size_t)row * 32 + ks * 8 + g * 2];
            float4 bb = x4[(size_t)row * 32 + ks * 8 + g * 2 + 1];
            float xv[8] = {a.x, a.y, a.z, a.w, bb.x, bb.y, bb.z, bb.w};
#pragma unroll
            for (int j = 0; j < 8; j++) {
                _Float16 hh = (_Float16)xv[j];
                hiA[t][ks][j] = hh;
                loA[t][ks][j] = (_Float16)((xv[j] - (float)hh) * 4096.0f);
                ssum += xv[j] * xv[j];
            }
            if (ks == 3 && g == 3) { tl = xv[7]; ssum -= xv[7] * xv[7]; }
        }
        ssum += __shfl_xor(ssum, 16);
        ssum += __shfl_xor(ssum, 32);
        float rn = 1.f / fmaxf(sqrtf(ssum), EPSF);
        float tla = __shfl(tl, 48 + r);        // x127 of row (t, r)
        float tc = tla * (1.f - rn);
#pragma unroll
        for (int j = 0; j < 4; j++) {
            rnj[t][j] = __shfl(rn, g * 4 + j);
            tcj[t][j] = __shfl(tc, g * 4 + j);
        }
    }

    asm volatile("s_waitcnt vmcnt(0)" ::: "memory");
    __syncthreads();                  // phase-0 B resident in LDS

    const float* const bks[3] = {bq, bk, bv};
    bool lane15 = (r == 15);
    const f32x4 zz = {0.f, 0.f, 0.f, 0.f};
    int dsb = g * 64 + r;             // half8-slot base for this lane (within phase)

#pragma unroll
    for (int kind = 0; kind < 3; kind++) {
#pragma unroll
        for (int h = 0; h < 2; h++) {
            int ph = kind * 2 + h;    // phase 0..5
            float wcA[4], bbA[4];
#pragma unroll
            for (int ct = 0; ct < 4; ct++) {
                int col = (h * 4 + ct) * 16 + r;
                wcA[ct] = w127[kind * 128 + col];
                bbA[ct] = bks[kind][col];
            }

            f32x4 aM[2][4], aX[2][4];
#pragma unroll
            for (int t = 0; t < 2; t++)
#pragma unroll
                for (int ct = 0; ct < 4; ct++) { aM[t][ct] = zz; aX[t][ct] = zz; }

#pragma unroll
            for (int ks = 0; ks < 4; ks++) {
                half8 hB[4], lB[4];
#pragma unroll
                for (int ct = 0; ct < 4; ct++) {
                    int bi = ks * 256 + dsb + ct * 16;
                    hB[ct] = bsh[bi];
                    lB[ct] = bsh[1024 + bi];
                }
#pragma unroll
                for (int ct = 0; ct < 4; ct++) {
                    aM[0][ct] = __builtin_amdgcn_mfma_f32_16x16x32_f16(hiA[0][ks], hB[ct], aM[0][ct], 0, 0, 0);
                    aM[1][ct] = __builtin_amdgcn_mfma_f32_16x16x32_f16(hiA[1][ks], hB[ct], aM[1][ct], 0, 0, 0);
                    aX[0][ct] = __builtin_amdgcn_mfma_f32_16x16x32_f16(hiA[0][ks], lB[ct], aX[0][ct], 0, 0, 0);
                    aX[0][ct] = __builtin_amdgcn_mfma_f32_16x16x32_f16(loA[0][ks], hB[ct], aX[0][ct], 0, 0, 0);
                    aX[1][ct] = __builtin_amdgcn_mfma_f32_16x16x32_f16(hiA[1][ks], lB[ct], aX[1][ct], 0, 0, 0);
                    aX[1][ct] = __builtin_amdgcn_mfma_f32_16x16x32_f16(loA[1][ks], hB[ct], aX[1][ct], 0, 0, 0);
                }
            }

            // last bsh read of this phase done: issue next-phase staging so its
            // L2 latency hides under the (register-only) epilogue below.
            if (ph < 5) {
                __syncthreads();      // all waves done reading bsh this phase
                const half8* sH = whi + (ph + 1) * 1024 + wv * 256;
                const half8* sL = wlo + (ph + 1) * 1024 + wv * 256;
#pragma unroll
                for (int i = 0; i < 4; i++) {
                    gl_lds16(sH + i * 64 + l, bsh + wv * 256 + i * 64);
                    gl_lds16(sL + i * 64 + l, bsh + 1024 + wv * 256 + i * 64);
                }
            }

            // epilogue for (kind, head h): combine, norm-correct, normalize, store
#pragma unroll
            for (int t = 0; t < 2; t++) {
                float cv[4][4];       // [ct][j]
#pragma unroll
                for (int ct = 0; ct < 4; ct++)
#pragma unroll
                    for (int j = 0; j < 4; j++) {
                        float acc = aM[t][ct][j] + aX[t][ct][j] * (1.0f / 4096.0f);
                        cv[ct][j] = fmaf(rnj[t][j], acc, fmaf(tcj[t][j], wcA[ct], bbA[ct]));
                    }
                if (kind < 2) {
#pragma unroll
                    for (int j = 0; j < 4; j++) {
                        float ss = 0.f;
#pragma unroll
                        for (int ct = 0; ct < 4; ct++) {
                            float c = cv[ct][j];
                            ss += (ct == 3 && lane15) ? 0.f : c * c;
                        }
                        ss += __shfl_xor(ss, 1);
                        ss += __shfl_xor(ss, 2);
                        ss += __shfl_xor(ss, 4);
                        ss += __shfl_xor(ss, 8);
                        float rh = 1.f / fmaxf(sqrtf(ss), EPSF);
#pragma unroll
                        for (int ct = 0; ct < 4; ct++) {
                            bool ist = (ct == 3) && lane15;
                            if (!ist) cv[ct][j] *= rh;
                            if (kind == 0) {
                                if (ist) cv[ct][j] = -cv[ct][j];
                                cv[ct][j] *= INV_SQRT128;
                            }
                        }
                    }
                }
#pragma unroll
                for (int j = 0; j < 4; j++) {
                    int row = rowbase + t * 16 + g * 4 + j;
                    if (row < N) {
                        if (kind == 0) {
                            float* dst = qn + (size_t)row * 128;
#pragma unroll
                            for (int ct = 0; ct < 4; ct++)
                                dst[(h * 4 + ct) * 16 + r] = cv[ct][j];
                        } else if (kind == 1) {
                            _Float16* dst = knh + (size_t)row * 128;
#pragma unroll
                            for (int ct = 0; ct < 4; ct++)
                                dst[(h * 4 + ct) * 16 + r] = (_Float16)cv[ct][j];
                        } else {
                            float* dst = vn + (size_t)row * 128;
#pragma unroll
                            for (int ct = 0; ct < 4; ct++)
                                dst[(h * 4 + ct) * 16 + r] = cv[ct][j];
                        }
                    }
                }
            }

            if (ph < 5) {             // staging was issued above; wait for it
                asm volatile("s_waitcnt vmcnt(0)" ::: "memory");
                __syncthreads();
            }
        }
    }
}

// ---------------- CSR build via 2-pass LDS counting sort (NO global atomics) ----------
__global__ void k_bin2(int* __restrict__ bcnt, int* __restrict__ bintot) {
    __shared__ int sd[256];
    int b = blockIdx.x, t = threadIdx.x;
    int v = bcnt[t * 256 + b];
    sd[t] = v;
    __syncthreads();
    for (int off = 1; off < 256; off <<= 1) {
        int val = sd[t];
        int add = (t >= off) ? sd[t - off] : 0;
        __syncthreads();
        sd[t] = val + add;
        __syncthreads();
    }
    bcnt[t * 256 + b] = sd[t] - v;    // exclusive
    if (t == 255) bintot[b] = sd[255];
}

__global__ void k_bin3(const int* __restrict__ bintot, int* __restrict__ binoff,
                       int* __restrict__ offs, int N, int E) {
    __shared__ int sd[256];
    int t = threadIdx.x;
    int v = bintot[t];
    sd[t] = v;
    __syncthreads();
    for (int off = 1; off < 256; off <<= 1) {
        int val = sd[t];
        int add = (t >= off) ? sd[t - off] : 0;
        __syncthreads();
        sd[t] = val + add;
        __syncthreads();
    }
    binoff[t] = sd[t] - v;
    if (t == 255) {
        binoff[256] = sd[255];
        offs[N] = E;
    }
}

__global__ void k_scat1(const int* __restrict__ ei, const int* __restrict__ bcnt,
                        const int* __restrict__ binoff, int* __restrict__ packed,
                        int E, int chunk) {
    __shared__ int cur[256];
    int t = threadIdx.x, b = blockIdx.x;
    cur[t] = binoff[t] + bcnt[b * 256 + t];
    __syncthreads();
    int s = b * chunk, e1 = min(s + chunk, E);
    for (int e = s + t; e < e1; e += 256) {
        int r = ei[e];
        int c = ei[E + e];
        int p = atomicAdd(&cur[r >> 9], 1);
        packed[p] = ((r & 511) << 17) | c;
    }
}

__global__ void __launch_bounds__(256)
k_sortf(const int* __restrict__ packed, const int* __restrict__ binoff,
        int* __restrict__ ccol, int* __restrict__ offs, int N) {
    __shared__ int seg[6656];         // bin size ~5120 +- 72; 6656 = +21 sigma
    __shared__ int h[512];
    __shared__ int sc[256];
    int b = blockIdx.x, t = threadIdx.x;
    int s = binoff[b], e1 = binoff[b + 1];
    int cnt = min(e1 - s, 6656);
    for (int i = t; i < cnt; i += 256) seg[i] = packed[s + i];
    h[t] = 0;
    h[t + 256] = 0;
    __syncthreads();
    for (int i = t; i < cnt; i += 256) atomicAdd(&h[seg[i] >> 17], 1);
    __syncthreads();
    int v0 = h[2 * t], v1 = h[2 * t + 1];
    int pair = v0 + v1;
    sc[t] = pair;
    __syncthreads();
    for (int off = 1; off < 256; off <<= 1) {
        int val = sc[t];
        int add = (t >= off) ? sc[t - off] : 0;
        __syncthreads();
        sc[t] = val + add;
        __syncthreads();
    }
    int pexcl = sc[t] - pair;
    __syncthreads();
    h[2 * t] = pexcl;
    h[2 * t + 1] = pexcl + v0;
    int rowbase = b << 9;
    if (rowbase + 2 * t < N) offs[rowbase + 2 * t] = s + h[2 * t];
    if (rowbase + 2 * t + 1 < N) offs[rowbase + 2 * t + 1] = s + h[2 * t + 1];
    __syncthreads();
    for (int i = t; i < cnt; i += 256) {
        int pk = seg[i];
        int p = atomicAdd(&h[pk >> 17], 1);
        ccol[s + p] = pk & 0x1FFFF;
    }
}

// ---------------- edge pass 1: scores + exp -> e2[head*E + i], per-block expsums ----
__global__ void k_score(const float* __restrict__ qn, const _Float16* __restrict__ knh,
                        const int* __restrict__ offs, const int* __restrict__ ccol,
                        float* __restrict__ e2, double* __restrict__ psum, int N, int E) {
    int g = threadIdx.x >> 5;            // 8 nodes/block
    int l = threadIdx.x & 31;
    int head = l >> 4;
    int n = blockIdx.x * 8 + g;
    double esum = 0.0;
    if (n < N) {
        float4 q4 = ((const float4*)qn)[(size_t)n * 32 + l];
        int s0 = offs[n], s1 = offs[n + 1];
        const half4v* k4p = (const half4v*)knh;
        float* eh = e2 + (size_t)head * E;
        int i = s0;
        for (; i + 4 <= s1; i += 4) {
            int c0 = ccol[i];
            int c1 = ccol[i + 1];
            int c2 = ccol[i + 2];
            int c3 = ccol[i + 3];
            half4v ka = k4p[(size_t)c0 * 32 + l];
            half4v kb = k4p[(size_t)c1 * 32 + l];
            half4v kc = k4p[(size_t)c2 * 32 + l];
            half4v kd = k4p[(size_t)c3 * 32 + l];
            float p0 = q4.x * (float)ka[0];
            p0 = fmaf(q4.y, (float)ka[1], p0); p0 = fmaf(q4.z, (float)ka[2], p0);
            p0 = fmaf(q4.w, (float)ka[3], p0);
            float p1 = q4.x * (float)kb[0];
            p1 = fmaf(q4.y, (float)kb[1], p1); p1 = fmaf(q4.z, (float)kb[2], p1);
            p1 = fmaf(q4.w, (float)kb[3], p1);
            float p2 = q4.x * (float)kc[0];
            p2 = fmaf(q4.y, (float)kc[1], p2); p2 = fmaf(q4.z, (float)kc[2], p2);
            p2 = fmaf(q4.w, (float)kc[3], p2);
            float p3 = q4.x * (float)kd[0];
            p3 = fmaf(q4.y, (float)kd[1], p3); p3 = fmaf(q4.z, (float)kd[2], p3);
            p3 = fmaf(q4.w, (float)kd[3], p3);
            p0 += __shfl_xor(p0, 1); p1 += __shfl_xor(p1, 1);
            p2 += __shfl_xor(p2, 1); p3 += __shfl_xor(p3, 1);
            p0 += __shfl_xor(p0, 2); p1 += __shfl_xor(p1, 2);
            p2 += __shfl_xor(p2, 2); p3 += __shfl_xor(p3, 2);
            p0 += __shfl_xor(p0, 4); p1 += __shfl_xor(p1, 4);
            p2 += __shfl_xor(p2, 4); p3 += __shfl_xor(p3, 4);
            p0 += __shfl_xor(p0, 8); p1 += __shfl_xor(p1, 8);
            p2 += __shfl_xor(p2, 8); p3 += __shfl_xor(p3, 8);
            float x0 = expf(p0);
            float x1 = expf(p1);
            float x2 = expf(p2);
            float x3 = expf(p3);
            if ((l & 15) == 0) {
                eh[i] = x0;
                eh[i + 1] = x1;
                eh[i + 2] = x2;
                eh[i + 3] = x3;
                esum += (double)((x0 + x1) + (x2 + x3));
            }
        }
        for (; i < s1; i++) {
            int c = ccol[i];
            half4v k4 = k4p[(size_t)c * 32 + l];
            float p = q4.x * (float)k4[0];
            p = fmaf(q4.y, (float)k4[1], p); p = fmaf(q4.z, (float)k4[2], p);
            p = fmaf(q4.w, (float)k4[3], p);
            p += __shfl_xor(p, 1);
            p += __shfl_xor(p, 2);
            p += __shfl_xor(p, 4);
            p += __shfl_xor(p, 8);
            float xx = expf(p);
            if ((l & 15) == 0) {
                eh[i] = xx;
                esum += (double)xx;
            }
        }
    }
    __shared__ double sd[2][8];
    if ((l & 15) == 0) sd[head][g] = esum;
    __syncthreads();
    if (threadIdx.x < 2) {
        double s = 0.0;
        for (int i2 = 0; i2 < 8; i2++) s += sd[threadIdx.x][i2];
        psum[(size_t)blockIdx.x * 2 + threadIdx.x] = s;
    }
}

// ---------------- edge pass 2: aggregate U = sum e * v (gathers ONLY v, fp32) --------
__global__ void k_aggr(const float* __restrict__ vn, const int* __restrict__ offs,
                       const int* __restrict__ ccol, const float* __restrict__ e2,
                       float* __restrict__ U, int N, int E) {
    int g = threadIdx.x >> 5;
    int l = threadIdx.x & 31;
    int head = l >> 4;
    int n = blockIdx.x * 8 + g;
    if (n >= N) return;
    int s0 = offs[n], s1 = offs[n + 1];
    const float4* v4p = (const float4*)vn;
    const float* eh = e2 + (size_t)head * E;
    float4 acc = {0.f, 0.f, 0.f, 0.f};
    int i = s0;
    for (; i + 4 <= s1; i += 4) {
        int c0 = ccol[i];
        int c1 = ccol[i + 1];
        int c2 = ccol[i + 2];
        int c3 = ccol[i + 3];
        float4 va = v4p[(size_t)c0 * 32 + l];
        float4 vb = v4p[(size_t)c1 * 32 + l];
        float4 vc = v4p[(size_t)c2 * 32 + l];
        float4 vd = v4p[(size_t)c3 * 32 + l];
        float x0 = eh[i];
        float x1 = eh[i + 1];
        float x2 = eh[i + 2];
        float x3 = eh[i + 3];
        acc.x = fmaf(va.x, x0, acc.x); acc.y = fmaf(va.y, x0, acc.y);
        acc.z = fmaf(va.z, x0, acc.z); acc.w = fmaf(va.w, x0, acc.w);
        acc.x = fmaf(vb.x, x1, acc.x); acc.y = fmaf(vb.y, x1, acc.y);
        acc.z = fmaf(vb.z, x1, acc.z); acc.w = fmaf(vb.w, x1, acc.w);
        acc.x = fmaf(vc.x, x2, acc.x); acc.y = fmaf(vc.y, x2, acc.y);
        acc.z = fmaf(vc.z, x2, acc.z); acc.w = fmaf(vc.w, x2, acc.w);
        acc.x = fmaf(vd.x, x3, acc.x); acc.y = fmaf(vd.y, x3, acc.y);
        acc.z = fmaf(vd.z, x3, acc.z); acc.w = fmaf(vd.w, x3, acc.w);
    }
    for (; i < s1; i++) {
        int c = ccol[i];
        float4 v4 = v4p[(size_t)c * 32 + l];
        float xx = eh[i];
        acc.x = fmaf(v4.x, xx, acc.x); acc.y = fmaf(v4.y, xx, acc.y);
        acc.z = fmaf(v4.z, xx, acc.z); acc.w = fmaf(v4.w, xx, acc.w);
    }
    ((float4*)U)[(size_t)n * 32 + l] = acc;
}

// ---------------- psum reduce + cr_initial + rows 0-3 of out + scale factor ----------
__global__ void k_crout4(const float* __restrict__ x, const float* __restrict__ U,
                         const float* __restrict__ Wo, const float* __restrict__ bo,
                         const double* __restrict__ psum, int P,
                         double* __restrict__ sumf, float* __restrict__ scalef) {
    __shared__ float xs[4 * 128];
    __shared__ float o4[4 * 64];
    __shared__ double crin_sh;
    __shared__ double sdr[2][4];
    int tid = threadIdx.x;  // 256
    {
        double s0 = 0.0, s1 = 0.0;
        for (int i = tid; i < P; i += 256) {
            s0 += psum[2 * i];
            s1 += psum[2 * i + 1];
        }
        for (int off = 32; off; off >>= 1) {
            s0 += __shfl_xor(s0, off);
            s1 += __shfl_xor(s1, off);
        }
        int w = tid >> 6;
        if ((tid & 63) == 0) { sdr[0][w] = s0; sdr[1][w] = s1; }
    }
    xs[tid] = U[tid];
    xs[tid + 256] = U[tid + 256];
    __syncthreads();
    if (tid == 0) {
        double s0 = sdr[0][0] + sdr[0][1] + sdr[0][2] + sdr[0][3];
        double s1 = sdr[1][0] + sdr[1][1] + sdr[1][2] + sdr[1][3];
        sumf[0] = s0;
        sumf[1] = s1;
    }
    if (tid >= 64 && tid < 128) {   // wave 1: cross-ratio of raw x rows 0..3
        int l = tid - 64;
        const int pa[4] = {0, 1, 0, 1};
        const int pb[4] = {2, 3, 3, 2};
        double inner[4];
        for (int p = 0; p < 4; p++) {
            const float* a = x + pa[p] * 128;
            const float* b = x + pb[p] * 128;
            double s = (double)a[l] * (double)b[l];
            double t = (double)a[l + 64] * (double)b[l + 64];
            s += (l == 63) ? -t : t;
            for (int off = 32; off; off >>= 1) s += __shfl_xor(s, off);
            inner[p] = s;
        }
        if (l == 0) {
            double num = inner[0] * inner[1];
            double den = inner[2] * inner[3];
            if (fabs(den) < 1e-9) den = 1e-9;
            crin_sh = num / den;
        }
    }
    __syncthreads();
    int w = tid >> 6, o = tid & 63;
    float si0 = (float)(1.0 / sumf[0]);
    float si1 = (float)(1.0 / sumf[1]);
    const float* xr = xs + w * 128;
    const float* wr = Wo + (size_t)o * 128;
    float d0 = 0.f, d1 = 0.f;
    for (int j = 0; j < 64; j++) d0 = fmaf(xr[j], wr[j], d0);
    for (int j = 64; j < 128; j++) d1 = fmaf(xr[j], wr[j], d1);
    o4[w * 64 + o] = d0 * si0 + d1 * si1 + bo[o];
    __syncthreads();
    if (tid < 64) {
        int l = tid;
        const int pa[4] = {0, 1, 0, 1};
        const int pb[4] = {2, 3, 3, 2};
        double inner[4];
        for (int p = 0; p < 4; p++) {
            double t = (double)o4[pa[p] * 64 + l] * (double)o4[pb[p] * 64 + l];
            if (l == 63) t = -t;
            for (int off = 32; off; off >>= 1) t += __shfl_xor(t, off);
            inner[p] = t;
        }
        if (l == 0) {
            double num = inner[0] * inner[1];
            double den = inner[2] * inner[3];
            if (fabs(den) < 1e-9) den = 1e-9;
            double crc = num / den;
            if (fabs(crc) < 1e-9) crc = 1e-9;
            double ratio = crin_sh / crc;
            scalef[0] = (float)pow(fabs(ratio), 0.25);
        }
    }
}

// ---------------- final GEMM via split-fp16 MFMA: out = ((U/sumf)@Wo.T + bo)*scalef ----
__global__ void __launch_bounds__(256, 2)
k_outm(const float* __restrict__ U, const half8* __restrict__ wohi,
       const half8* __restrict__ wolo, const float* __restrict__ bo,
       const double* __restrict__ sumf, const float* __restrict__ scalef,
       float* __restrict__ out, int N) {
    __shared__ half8 bsh[2048];       // 32 KB: [0..1024) hi, [1024..2048) lo
    int tid = threadIdx.x;
    int wv = tid >> 6;                // wave 0..3
    int l = tid & 63;
    int r = l & 15;
    int g = l >> 4;
    int rowbase = blockIdx.x * 128 + wv * 32;

    {   // stage Wo frags
        const half8* sH = wohi + wv * 256;
        const half8* sL = wolo + wv * 256;
#pragma unroll
        for (int i = 0; i < 4; i++) {
            gl_lds16(sH + i * 64 + l, bsh + wv * 256 + i * 64);
            gl_lds16(sL + i * 64 + l, bsh + 1024 + wv * 256 + i * 64);
        }
    }

    float si0 = (float)(1.0 / sumf[0]);
    float si1 = (float)(1.0 / sumf[1]);
    const float4* U4 = (const float4*)U;
    half8 hiA[2][4], loA[2][4];
#pragma unroll
    for (int t = 0; t < 2; t++) {
        int row = min(rowbase + t * 16 + r, N - 1);
#pragma unroll
        for (int ks = 0; ks < 4; ks++) {
            float si = (ks < 2) ? si0 : si1;
            float4 a = U4[(size_t)row * 32 + ks * 8 + g * 2];
            float4 b = U4[(size_t)row * 32 + ks * 8 + g * 2 + 1];
            float xv[8] = {a.x, a.y, a.z, a.w, b.x, b.y, b.z, b.w};
#pragma unroll
            for (int j = 0; j < 8; j++) {
                float v = xv[j] * si;
                _Float16 hh = (_Float16)v;
                hiA[t][ks][j] = hh;
                loA[t][ks][j] = (_Float16)((v - (float)hh) * 4096.0f);
            }
        }
    }

    asm volatile("s_waitcnt vmcnt(0)" ::: "memory");
    __syncthreads();

    const f32x4 zz = {0.f, 0.f, 0.f, 0.f};
    f32x4 aM[2][4], aX[2][4];
#pragma unroll
    for (int t = 0; t < 2; t++)
#pragma unroll
        for (int ct = 0; ct < 4; ct++) { aM[t][ct] = zz; aX[t][ct] = zz; }

#pragma unroll
    for (int ks = 0; ks < 4; ks++) {
        half8 hB[4], lB[4];
#pragma unroll
        for (int ct = 0; ct < 4; ct++) {
            int bi = ks * 256 + g * 64 + ct * 16 + r;
            hB[ct] = bsh[bi];
            lB[ct] = bsh[1024 + bi];
        }
#pragma unroll
        for (int ct = 0; ct < 4; ct++) {
            aM[0][ct] = __builtin_amdgcn_mfma_f32_16x16x32_f16(hiA[0][ks], hB[ct], aM[0][ct], 0, 0, 0);
            aM[1][ct] = __builtin_amdgcn_mfma_f32_16x16x32_f16(hiA[1][ks], hB[ct], aM[1][ct], 0, 0, 0);
            aX[0][ct] = __builtin_amdgcn_mfma_f32_16x16x32_f16(hiA[0][ks], lB[ct], aX[0][ct], 0, 0, 0);
            aX[0][ct] = __builtin_amdgcn_mfma_f32_16x16x32_f16(loA[0][ks], hB[ct], aX[0][ct], 0, 0, 0);
            aX[1][ct] = __builtin_amdgcn_mfma_f32_16x16x32_f16(hiA[1][ks], lB[ct], aX[1][ct], 0, 0, 0);
            aX[1][ct] = __builtin_amdgcn_mfma_f32_16x16x32_f16(loA[1][ks], hB[ct], aX[1][ct], 0, 0, 0);
        }
    }

    float sf = scalef[0];
#pragma unroll
    for (int t = 0; t < 2; t++)
#pragma unroll
        for (int ct = 0; ct < 4; ct++) {
            float bb = bo[ct * 16 + r];
#pragma unroll
            for (int j = 0; j < 4; j++) {
                int row = rowbase + t * 16 + g * 4 + j;
                if (row < N) {
                    float c = (aM[t][ct][j] + aX[t][ct][j] * (1.0f / 4096.0f) + bb) * sf;
                    out[(size_t)row * 64 + ct * 16 + r] = c;
                }
            }
        }
}

extern "C" void kernel_launch(void* const* d_in, const int* in_sizes, int n_in,
                              void* d_out, int out_size, void* d_ws, size_t ws_size,
                              hipStream_t stream) {
    const float* x  = (const float*)d_in[0];
    const int*   ei = (const int*)d_in[1];
    const float* Wq = (const float*)d_in[2];
    const float* bq = (const float*)d_in[3];
    const float* Wk = (const float*)d_in[4];
    const float* bk = (const float*)d_in[5];
    const float* Wv = (const float*)d_in[6];
    const float* bv = (const float*)d_in[7];
    const float* Wo = (const float*)d_in[8];
    const float* bo = (const float*)d_in[9];
    float* out = (float*)d_out;

    const int N = in_sizes[0] / 128;   // 100000
    const int E = in_sizes[1] / 2;     // 1000000
    const size_t NR = (size_t)N * 128;
    const int NGB = (N + 127) / 128;   // 782 GEMM blocks (128 rows each)
    const int GB = (N + 7) / 8;        // 12500 edge-pass blocks
    const int chunk = (E + 255) / 256; // pass-1 sort chunk (256 chunks)
    const int NBINS = (N + 511) >> 9;  // 196 coarse bins (row>>9)

    float* qn = (float*)d_ws;          // N*128 f32 ; reused as U after edge passes
    float* vn = qn + NR;               // N*128 f32
    _Float16* knh = (_Float16*)(vn + NR);      // N*128 f16
    int* offs = (int*)(knh + NR);              // N+1
    int* ccol = offs + N + 2;                  // E (also packed tmp for the sort)
    int* bcnt = ccol + E;                      // 256*256
    int* bintot = bcnt + 256 * 256;            // 256
    int* binoff = bintot + 256;                // 257
    uintptr_t pe = ((uintptr_t)(binoff + 257 + 1) + 15) & ~(uintptr_t)15;
    float* e2 = (float*)pe;                    // 2*E per-head exp scores
    uintptr_t pd = ((uintptr_t)(e2 + 2 * (size_t)E) + 7) & ~(uintptr_t)7;
    double* psum = (double*)pd;                // GB*2 partial expsums
    double* sumf = psum + (size_t)GB * 2;      // 2
    float* scalef = (float*)(sumf + 2);        // 1

    // packed Wq/Wk/Wv frags alias ccol (dead until k_scat1, consumed by k_qkvm first)
    uintptr_t pw = ((uintptr_t)ccol + 15) & ~(uintptr_t)15;
    half8* whi = (half8*)pw;                   // 6144 * 16B
    half8* wlo = whi + 6144;                   // 6144 * 16B
    float* w127 = (float*)(wlo + 6144);        // 3*128 floats

    // packed Wo frags alias bcnt (dead after k_scat1; k_wpack2 runs after it)
    uintptr_t pw2 = ((uintptr_t)bcnt + 15) & ~(uintptr_t)15;
    half8* wohi = (half8*)pw2;                 // 1024 * 16B
    half8* wolo = wohi + 1024;                 // 1024 * 16B

    float* U = qn;  // aggregation output aliases q (q consumed by k_score)

    k_wpack<<<24, 256, 0, stream>>>(Wq, Wk, Wv, whi, wlo, w127);
    k_qkvm<<<NGB + 256, 256, 0, stream>>>(x, whi, wlo, w127, bq, bk, bv,
                                          qn, knh, vn, ei, bcnt, N, E, chunk);
    k_bin2<<<256, 256, 0, stream>>>(bcnt, bintot);
    k_bin3<<<1, 256, 0, stream>>>(bintot, binoff, offs, N, E);
    k_scat1<<<256, 256, 0, stream>>>(ei, bcnt, binoff, ccol, E, chunk);
    k_wpack2<<<4, 256, 0, stream>>>(Wo, wohi, wolo);   // bcnt space now dead
    k_sortf<<<NBINS, 256, 0, stream>>>(ccol, binoff, ccol, offs, N);
    k_score<<<GB, 256, 0, stream>>>(qn, knh, offs, ccol, e2, psum, N, E);
    k_aggr<<<GB, 256, 0, stream>>>(vn, offs, ccol, e2, U, N, E);
    k_crout4<<<1, 256, 0, stream>>>(x, U, Wo, bo, psum, GB, sumf, scalef);
    k_outm<<<NGB, 256, 0, stream>>>(U, wohi, wolo, bo, sumf, scalef, out, N);
}

// Round 11
// 374.888 us; speedup vs baseline: 1.2602x; 1.2602x over previous
//
#include <hip/hip_runtime.h>
#include <math.h>

#define EPSF 1e-9f
#define INV_SQRT128 0.08838834764831845f

typedef _Float16 half8 __attribute__((ext_vector_type(8)));
typedef _Float16 half4v __attribute__((ext_vector_type(4)));
typedef float f32x4 __attribute__((ext_vector_type(4)));

// async global->LDS, 16B per lane: lane l reads g[l], HW writes lds_base + l*16
__device__ __forceinline__ void gl_lds16(const void* g, void* l) {
    __builtin_amdgcn_global_load_lds((const __attribute__((address_space(1))) void*)g,
                                     (__attribute__((address_space(3))) void*)l, 16, 0, 0);
}

// ---------------- W pre-pack: fp32 -> (hi fp16, lo fp16*4096) MFMA B-fragments ----------
// R10 layout: slot t = kind*2048 + h*1024 + ks*256 + g*64 + col'  (col = h*64+col').
// Each (kind, head) owns a contiguous 1024-slot (16 KB) segment so k_qkvm can stage
// 32 KB (hi+lo) per phase instead of 64 KB.
__global__ void k_wpack(const float* __restrict__ Wq, const float* __restrict__ Wk,
                        const float* __restrict__ Wv, half8* __restrict__ whi,
                        half8* __restrict__ wlo, float* __restrict__ w127) {
    int t = blockIdx.x * 256 + threadIdx.x;   // 6144 items
    if (t >= 6144) return;
    int colp = t & 63, g = (t >> 6) & 3, ks = (t >> 8) & 3, h = (t >> 10) & 1, kind = t >> 11;
    int col = h * 64 + colp;
    const float* W = (kind == 0) ? Wq : (kind == 1) ? Wk : Wv;
    const float4* W4 = (const float4*)W;
    float4 a = W4[col * 32 + ks * 8 + g * 2];
    float4 b = W4[col * 32 + ks * 8 + g * 2 + 1];
    float xv[8] = {a.x, a.y, a.z, a.w, b.x, b.y, b.z, b.w};
    half8 hh8, lo;
#pragma unroll
    for (int j = 0; j < 8; j++) {
        _Float16 hh = (_Float16)xv[j];
        hh8[j] = hh;
        lo[j] = (_Float16)((xv[j] - (float)hh) * 4096.0f);
    }
    whi[t] = hh8;
    wlo[t] = lo;
    if (ks == 3 && g == 3) w127[kind * 128 + col] = xv[7];   // W[col][127]
}

// ---------------- Wo pre-pack (for k_outm): slot t=(ks*4+g)*64+col ----------
__global__ void k_wpack2(const float* __restrict__ Wo, half8* __restrict__ wohi,
                         half8* __restrict__ wolo) {
    int t = blockIdx.x * 256 + threadIdx.x;   // 1024 items
    if (t >= 1024) return;
    int col = t & 63, g = (t >> 6) & 3, ks = t >> 8;
    const float4* W4 = (const float4*)Wo;
    float4 a = W4[col * 32 + ks * 8 + g * 2];
    float4 b = W4[col * 32 + ks * 8 + g * 2 + 1];
    float xv[8] = {a.x, a.y, a.z, a.w, b.x, b.y, b.z, b.w};
    half8 h, lo;
#pragma unroll
    for (int j = 0; j < 8; j++) {
        _Float16 hh = (_Float16)xv[j];
        h[j] = hh;
        lo[j] = (_Float16)((xv[j] - (float)hh) * 4096.0f);
    }
    wohi[t] = h;
    wolo[t] = lo;
}

// ---------------- fused qkv via split-fp16 MFMA, B staged in LDS ----------------
// R11: R10's 6-phase (kind, head) split (32 KB LDS/phase) with the R9-proven
// __launch_bounds__(256,2) -- R10's (256,4) forced the 128-reg live set into 64
// VGPRs and spilled (FETCH 32->240 MB, dur 91->203). With 32 KB LDS + natural
// 128 VGPR: occupancy limit = min(LDS 5, VGPR 4) = 4 blocks/CU = 4 waves/SIMD,
// the target regime, reached WITHOUT coercing the allocator.
__global__ void __launch_bounds__(256, 2)
k_qkvm(const float* __restrict__ x,
       const half8* __restrict__ whi, const half8* __restrict__ wlo,
       const float* __restrict__ w127,
       const float* __restrict__ bq, const float* __restrict__ bk,
       const float* __restrict__ bv,
       float* __restrict__ qn, _Float16* __restrict__ knh, float* __restrict__ vn,
       const int* __restrict__ ei, int* __restrict__ bcnt,
       int N, int E, int chunk) {
    int b = (int)blockIdx.x;
    __shared__ half8 bsh[2048];       // 32 KB: [0..1024) hi, [1024..2048) lo
    if (b < 512 && (b & 1)) {         // histogram role (per-chunk coarse counts)
        int* h = (int*)bsh;           // reuse GEMM staging LDS
        int t = threadIdx.x;          // 0..255
        int hid = b >> 1;             // 0..255
        h[t] = 0;
        __syncthreads();
        int s = hid * chunk, e1 = min(s + chunk, E);
        for (int e = s + t; e < e1; e += 256) atomicAdd(&h[ei[e] >> 9], 1);
        __syncthreads();
        bcnt[hid * 256 + t] = h[t];
        return;
    }
    int gb = (b < 512) ? (b >> 1) : (b - 256);   // GEMM block id 0..781

    int tid = threadIdx.x;
    int wv = tid >> 6;                // wave 0..3
    int l = tid & 63;
    int r = l & 15;                   // A-row / out-col lane index
    int g = l >> 4;                   // k-group / out-row group
    int rowbase = gb * 128 + wv * 32;
    const float4* x4 = (const float4*)x;

    // ---- issue phase-0 (kind0, head0) B staging (latency overlaps x processing) ----
    {
        const half8* sH = whi + wv * 256;
        const half8* sL = wlo + wv * 256;
#pragma unroll
        for (int i = 0; i < 4; i++) {
            gl_lds16(sH + i * 64 + l, bsh + wv * 256 + i * 64);
            gl_lds16(sL + i * 64 + l, bsh + 1024 + wv * 256 + i * 64);
        }
    }

    // ---- load x for 2 row-tiles, build hi/lo frags, fold normalization ----
    half8 hiA[2][4], loA[2][4];
    float rnj[2][4], tcj[2][4];
#pragma unroll
    for (int t = 0; t < 2; t++) {
        int row = min(rowbase + t * 16 + r, N - 1);
        float ssum = 0.f, tl = 0.f;
#pragma unroll
        for (int ks = 0; ks < 4; ks++) {
            float4 a = x4[(size_t)row * 32 + ks * 8 + g * 2];
            float4 bb = x4[(size_t)row * 32 + ks * 8 + g * 2 + 1];
            float xv[8] = {a.x, a.y, a.z, a.w, bb.x, bb.y, bb.z, bb.w};
#pragma unroll
            for (int j = 0; j < 8; j++) {
                _Float16 hh = (_Float16)xv[j];
                hiA[t][ks][j] = hh;
                loA[t][ks][j] = (_Float16)((xv[j] - (float)hh) * 4096.0f);
                ssum += xv[j] * xv[j];
            }
            if (ks == 3 && g == 3) { tl = xv[7]; ssum -= xv[7] * xv[7]; }
        }
        ssum += __shfl_xor(ssum, 16);
        ssum += __shfl_xor(ssum, 32);
        float rn = 1.f / fmaxf(sqrtf(ssum), EPSF);
        float tla = __shfl(tl, 48 + r);        // x127 of row (t, r)
        float tc = tla * (1.f - rn);
#pragma unroll
        for (int j = 0; j < 4; j++) {
            rnj[t][j] = __shfl(rn, g * 4 + j);
            tcj[t][j] = __shfl(tc, g * 4 + j);
        }
    }

    asm volatile("s_waitcnt vmcnt(0)" ::: "memory");
    __syncthreads();                  // phase-0 B resident in LDS

    const float* const bks[3] = {bq, bk, bv};
    bool lane15 = (r == 15);
    const f32x4 zz = {0.f, 0.f, 0.f, 0.f};
    int dsb = g * 64 + r;             // half8-slot base for this lane (within phase)

#pragma unroll
    for (int kind = 0; kind < 3; kind++) {
#pragma unroll
        for (int h = 0; h < 2; h++) {
            int ph = kind * 2 + h;    // phase 0..5
            float wcA[4], bbA[4];
#pragma unroll
            for (int ct = 0; ct < 4; ct++) {
                int col = (h * 4 + ct) * 16 + r;
                wcA[ct] = w127[kind * 128 + col];
                bbA[ct] = bks[kind][col];
            }

            f32x4 aM[2][4], aX[2][4];
#pragma unroll
            for (int t = 0; t < 2; t++)
#pragma unroll
                for (int ct = 0; ct < 4; ct++) { aM[t][ct] = zz; aX[t][ct] = zz; }

#pragma unroll
            for (int ks = 0; ks < 4; ks++) {
                half8 hB[4], lB[4];
#pragma unroll
                for (int ct = 0; ct < 4; ct++) {
                    int bi = ks * 256 + dsb + ct * 16;
                    hB[ct] = bsh[bi];
                    lB[ct] = bsh[1024 + bi];
                }
#pragma unroll
                for (int ct = 0; ct < 4; ct++) {
                    aM[0][ct] = __builtin_amdgcn_mfma_f32_16x16x32_f16(hiA[0][ks], hB[ct], aM[0][ct], 0, 0, 0);
                    aM[1][ct] = __builtin_amdgcn_mfma_f32_16x16x32_f16(hiA[1][ks], hB[ct], aM[1][ct], 0, 0, 0);
                    aX[0][ct] = __builtin_amdgcn_mfma_f32_16x16x32_f16(hiA[0][ks], lB[ct], aX[0][ct], 0, 0, 0);
                    aX[0][ct] = __builtin_amdgcn_mfma_f32_16x16x32_f16(loA[0][ks], hB[ct], aX[0][ct], 0, 0, 0);
                    aX[1][ct] = __builtin_amdgcn_mfma_f32_16x16x32_f16(hiA[1][ks], lB[ct], aX[1][ct], 0, 0, 0);
                    aX[1][ct] = __builtin_amdgcn_mfma_f32_16x16x32_f16(loA[1][ks], hB[ct], aX[1][ct], 0, 0, 0);
                }
            }

            // last bsh read of this phase done: issue next-phase staging so its
            // L2 latency hides under the (register-only) epilogue below.
            if (ph < 5) {
                __syncthreads();      // all waves done reading bsh this phase
                const half8* sH = whi + (ph + 1) * 1024 + wv * 256;
                const half8* sL = wlo + (ph + 1) * 1024 + wv * 256;
#pragma unroll
                for (int i = 0; i < 4; i++) {
                    gl_lds16(sH + i * 64 + l, bsh + wv * 256 + i * 64);
                    gl_lds16(sL + i * 64 + l, bsh + 1024 + wv * 256 + i * 64);
                }
            }

            // epilogue for (kind, head h): combine, norm-correct, normalize, store
#pragma unroll
            for (int t = 0; t < 2; t++) {
                float cv[4][4];       // [ct][j]
#pragma unroll
                for (int ct = 0; ct < 4; ct++)
#pragma unroll
                    for (int j = 0; j < 4; j++) {
                        float acc = aM[t][ct][j] + aX[t][ct][j] * (1.0f / 4096.0f);
                        cv[ct][j] = fmaf(rnj[t][j], acc, fmaf(tcj[t][j], wcA[ct], bbA[ct]));
                    }
                if (kind < 2) {
#pragma unroll
                    for (int j = 0; j < 4; j++) {
                        float ss = 0.f;
#pragma unroll
                        for (int ct = 0; ct < 4; ct++) {
                            float c = cv[ct][j];
                            ss += (ct == 3 && lane15) ? 0.f : c * c;
                        }
                        ss += __shfl_xor(ss, 1);
                        ss += __shfl_xor(ss, 2);
                        ss += __shfl_xor(ss, 4);
                        ss += __shfl_xor(ss, 8);
                        float rh = 1.f / fmaxf(sqrtf(ss), EPSF);
#pragma unroll
                        for (int ct = 0; ct < 4; ct++) {
                            bool ist = (ct == 3) && lane15;
                            if (!ist) cv[ct][j] *= rh;
                            if (kind == 0) {
                                if (ist) cv[ct][j] = -cv[ct][j];
                                cv[ct][j] *= INV_SQRT128;
                            }
                        }
                    }
                }
#pragma unroll
                for (int j = 0; j < 4; j++) {
                    int row = rowbase + t * 16 + g * 4 + j;
                    if (row < N) {
                        if (kind == 0) {
                            float* dst = qn + (size_t)row * 128;
#pragma unroll
                            for (int ct = 0; ct < 4; ct++)
                                dst[(h * 4 + ct) * 16 + r] = cv[ct][j];
                        } else if (kind == 1) {
                            _Float16* dst = knh + (size_t)row * 128;
#pragma unroll
                            for (int ct = 0; ct < 4; ct++)
                                dst[(h * 4 + ct) * 16 + r] = (_Float16)cv[ct][j];
                        } else {
                            float* dst = vn + (size_t)row * 128;
#pragma unroll
                            for (int ct = 0; ct < 4; ct++)
                                dst[(h * 4 + ct) * 16 + r] = cv[ct][j];
                        }
                    }
                }
            }

            if (ph < 5) {             // staging was issued above; wait for it
                asm volatile("s_waitcnt vmcnt(0)" ::: "memory");
                __syncthreads();
            }
        }
    }
}

// ---------------- CSR build via 2-pass LDS counting sort (NO global atomics) ----------
__global__ void k_bin2(int* __restrict__ bcnt, int* __restrict__ bintot) {
    __shared__ int sd[256];
    int b = blockIdx.x, t = threadIdx.x;
    int v = bcnt[t * 256 + b];
    sd[t] = v;
    __syncthreads();
    for (int off = 1; off < 256; off <<= 1) {
        int val = sd[t];
        int add = (t >= off) ? sd[t - off] : 0;
        __syncthreads();
        sd[t] = val + add;
        __syncthreads();
    }
    bcnt[t * 256 + b] = sd[t] - v;    // exclusive
    if (t == 255) bintot[b] = sd[255];
}

__global__ void k_bin3(const int* __restrict__ bintot, int* __restrict__ binoff,
                       int* __restrict__ offs, int N, int E) {
    __shared__ int sd[256];
    int t = threadIdx.x;
    int v = bintot[t];
    sd[t] = v;
    __syncthreads();
    for (int off = 1; off < 256; off <<= 1) {
        int val = sd[t];
        int add = (t >= off) ? sd[t - off] : 0;
        __syncthreads();
        sd[t] = val + add;
        __syncthreads();
    }
    binoff[t] = sd[t] - v;
    if (t == 255) {
        binoff[256] = sd[255];
        offs[N] = E;
    }
}

__global__ void k_scat1(const int* __restrict__ ei, const int* __restrict__ bcnt,
                        const int* __restrict__ binoff, int* __restrict__ packed,
                        int E, int chunk) {
    __shared__ int cur[256];
    int t = threadIdx.x, b = blockIdx.x;
    cur[t] = binoff[t] + bcnt[b * 256 + t];
    __syncthreads();
    int s = b * chunk, e1 = min(s + chunk, E);
    for (int e = s + t; e < e1; e += 256) {
        int r = ei[e];
        int c = ei[E + e];
        int p = atomicAdd(&cur[r >> 9], 1);
        packed[p] = ((r & 511) << 17) | c;
    }
}

__global__ void __launch_bounds__(256)
k_sortf(const int* __restrict__ packed, const int* __restrict__ binoff,
        int* __restrict__ ccol, int* __restrict__ offs, int N) {
    __shared__ int seg[6656];         // bin size ~5120 +- 72; 6656 = +21 sigma
    __shared__ int h[512];
    __shared__ int sc[256];
    int b = blockIdx.x, t = threadIdx.x;
    int s = binoff[b], e1 = binoff[b + 1];
    int cnt = min(e1 - s, 6656);
    for (int i = t; i < cnt; i += 256) seg[i] = packed[s + i];
    h[t] = 0;
    h[t + 256] = 0;
    __syncthreads();
    for (int i = t; i < cnt; i += 256) atomicAdd(&h[seg[i] >> 17], 1);
    __syncthreads();
    int v0 = h[2 * t], v1 = h[2 * t + 1];
    int pair = v0 + v1;
    sc[t] = pair;
    __syncthreads();
    for (int off = 1; off < 256; off <<= 1) {
        int val = sc[t];
        int add = (t >= off) ? sc[t - off] : 0;
        __syncthreads();
        sc[t] = val + add;
        __syncthreads();
    }
    int pexcl = sc[t] - pair;
    __syncthreads();
    h[2 * t] = pexcl;
    h[2 * t + 1] = pexcl + v0;
    int rowbase = b << 9;
    if (rowbase + 2 * t < N) offs[rowbase + 2 * t] = s + h[2 * t];
    if (rowbase + 2 * t + 1 < N) offs[rowbase + 2 * t + 1] = s + h[2 * t + 1];
    __syncthreads();
    for (int i = t; i < cnt; i += 256) {
        int pk = seg[i];
        int p = atomicAdd(&h[pk >> 17], 1);
        ccol[s + p] = pk & 0x1FFFF;
    }
}

// ---------------- edge pass 1: scores + exp -> e2[head*E + i], per-block expsums ----
__global__ void k_score(const float* __restrict__ qn, const _Float16* __restrict__ knh,
                        const int* __restrict__ offs, const int* __restrict__ ccol,
                        float* __restrict__ e2, double* __restrict__ psum, int N, int E) {
    int g = threadIdx.x >> 5;            // 8 nodes/block
    int l = threadIdx.x & 31;
    int head = l >> 4;
    int n = blockIdx.x * 8 + g;
    double esum = 0.0;
    if (n < N) {
        float4 q4 = ((const float4*)qn)[(size_t)n * 32 + l];
        int s0 = offs[n], s1 = offs[n + 1];
        const half4v* k4p = (const half4v*)knh;
        float* eh = e2 + (size_t)head * E;
        int i = s0;
        for (; i + 4 <= s1; i += 4) {
            int c0 = ccol[i];
            int c1 = ccol[i + 1];
            int c2 = ccol[i + 2];
            int c3 = ccol[i + 3];
            half4v ka = k4p[(size_t)c0 * 32 + l];
            half4v kb = k4p[(size_t)c1 * 32 + l];
            half4v kc = k4p[(size_t)c2 * 32 + l];
            half4v kd = k4p[(size_t)c3 * 32 + l];
            float p0 = q4.x * (float)ka[0];
            p0 = fmaf(q4.y, (float)ka[1], p0); p0 = fmaf(q4.z, (float)ka[2], p0);
            p0 = fmaf(q4.w, (float)ka[3], p0);
            float p1 = q4.x * (float)kb[0];
            p1 = fmaf(q4.y, (float)kb[1], p1); p1 = fmaf(q4.z, (float)kb[2], p1);
            p1 = fmaf(q4.w, (float)kb[3], p1);
            float p2 = q4.x * (float)kc[0];
            p2 = fmaf(q4.y, (float)kc[1], p2); p2 = fmaf(q4.z, (float)kc[2], p2);
            p2 = fmaf(q4.w, (float)kc[3], p2);
            float p3 = q4.x * (float)kd[0];
            p3 = fmaf(q4.y, (float)kd[1], p3); p3 = fmaf(q4.z, (float)kd[2], p3);
            p3 = fmaf(q4.w, (float)kd[3], p3);
            p0 += __shfl_xor(p0, 1); p1 += __shfl_xor(p1, 1);
            p2 += __shfl_xor(p2, 1); p3 += __shfl_xor(p3, 1);
            p0 += __shfl_xor(p0, 2); p1 += __shfl_xor(p1, 2);
            p2 += __shfl_xor(p2, 2); p3 += __shfl_xor(p3, 2);
            p0 += __shfl_xor(p0, 4); p1 += __shfl_xor(p1, 4);
            p2 += __shfl_xor(p2, 4); p3 += __shfl_xor(p3, 4);
            p0 += __shfl_xor(p0, 8); p1 += __shfl_xor(p1, 8);
            p2 += __shfl_xor(p2, 8); p3 += __shfl_xor(p3, 8);
            float x0 = expf(p0);
            float x1 = expf(p1);
            float x2 = expf(p2);
            float x3 = expf(p3);
            if ((l & 15) == 0) {
                eh[i] = x0;
                eh[i + 1] = x1;
                eh[i + 2] = x2;
                eh[i + 3] = x3;
                esum += (double)((x0 + x1) + (x2 + x3));
            }
        }
        for (; i < s1; i++) {
            int c = ccol[i];
            half4v k4 = k4p[(size_t)c * 32 + l];
            float p = q4.x * (float)k4[0];
            p = fmaf(q4.y, (float)k4[1], p); p = fmaf(q4.z, (float)k4[2], p);
            p = fmaf(q4.w, (float)k4[3], p);
            p += __shfl_xor(p, 1);
            p += __shfl_xor(p, 2);
            p += __shfl_xor(p, 4);
            p += __shfl_xor(p, 8);
            float xx = expf(p);
            if ((l & 15) == 0) {
                eh[i] = xx;
                esum += (double)xx;
            }
        }
    }
    __shared__ double sd[2][8];
    if ((l & 15) == 0) sd[head][g] = esum;
    __syncthreads();
    if (threadIdx.x < 2) {
        double s = 0.0;
        for (int i2 = 0; i2 < 8; i2++) s += sd[threadIdx.x][i2];
        psum[(size_t)blockIdx.x * 2 + threadIdx.x] = s;
    }
}

// ---------------- edge pass 2: aggregate U = sum e * v (gathers ONLY v, fp32) --------
__global__ void k_aggr(const float* __restrict__ vn, const int* __restrict__ offs,
                       const int* __restrict__ ccol, const float* __restrict__ e2,
                       float* __restrict__ U, int N, int E) {
    int g = threadIdx.x >> 5;
    int l = threadIdx.x & 31;
    int head = l >> 4;
    int n = blockIdx.x * 8 + g;
    if (n >= N) return;
    int s0 = offs[n], s1 = offs[n + 1];
    const float4* v4p = (const float4*)vn;
    const float* eh = e2 + (size_t)head * E;
    float4 acc = {0.f, 0.f, 0.f, 0.f};
    int i = s0;
    for (; i + 4 <= s1; i += 4) {
        int c0 = ccol[i];
        int c1 = ccol[i + 1];
        int c2 = ccol[i + 2];
        int c3 = ccol[i + 3];
        float4 va = v4p[(size_t)c0 * 32 + l];
        float4 vb = v4p[(size_t)c1 * 32 + l];
        float4 vc = v4p[(size_t)c2 * 32 + l];
        float4 vd = v4p[(size_t)c3 * 32 + l];
        float x0 = eh[i];
        float x1 = eh[i + 1];
        float x2 = eh[i + 2];
        float x3 = eh[i + 3];
        acc.x = fmaf(va.x, x0, acc.x); acc.y = fmaf(va.y, x0, acc.y);
        acc.z = fmaf(va.z, x0, acc.z); acc.w = fmaf(va.w, x0, acc.w);
        acc.x = fmaf(vb.x, x1, acc.x); acc.y = fmaf(vb.y, x1, acc.y);
        acc.z = fmaf(vb.z, x1, acc.z); acc.w = fmaf(vb.w, x1, acc.w);
        acc.x = fmaf(vc.x, x2, acc.x); acc.y = fmaf(vc.y, x2, acc.y);
        acc.z = fmaf(vc.z, x2, acc.z); acc.w = fmaf(vc.w, x2, acc.w);
        acc.x = fmaf(vd.x, x3, acc.x); acc.y = fmaf(vd.y, x3, acc.y);
        acc.z = fmaf(vd.z, x3, acc.z); acc.w = fmaf(vd.w, x3, acc.w);
    }
    for (; i < s1; i++) {
        int c = ccol[i];
        float4 v4 = v4p[(size_t)c * 32 + l];
        float xx = eh[i];
        acc.x = fmaf(v4.x, xx, acc.x); acc.y = fmaf(v4.y, xx, acc.y);
        acc.z = fmaf(v4.z, xx, acc.z); acc.w = fmaf(v4.w, xx, acc.w);
    }
    ((float4*)U)[(size_t)n * 32 + l] = acc;
}

// ---------------- psum reduce + cr_initial + rows 0-3 of out + scale factor ----------
__global__ void k_crout4(const float* __restrict__ x, const float* __restrict__ U,
                         const float* __restrict__ Wo, const float* __restrict__ bo,
                         const double* __restrict__ psum, int P,
                         double* __restrict__ sumf, float* __restrict__ scalef) {
    __shared__ float xs[4 * 128];
    __shared__ float o4[4 * 64];
    __shared__ double crin_sh;
    __shared__ double sdr[2][4];
    int tid = threadIdx.x;  // 256
    {
        double s0 = 0.0, s1 = 0.0;
        for (int i = tid; i < P; i += 256) {
            s0 += psum[2 * i];
            s1 += psum[2 * i + 1];
        }
        for (int off = 32; off; off >>= 1) {
            s0 += __shfl_xor(s0, off);
            s1 += __shfl_xor(s1, off);
        }
        int w = tid >> 6;
        if ((tid & 63) == 0) { sdr[0][w] = s0; sdr[1][w] = s1; }
    }
    xs[tid] = U[tid];
    xs[tid + 256] = U[tid + 256];
    __syncthreads();
    if (tid == 0) {
        double s0 = sdr[0][0] + sdr[0][1] + sdr[0][2] + sdr[0][3];
        double s1 = sdr[1][0] + sdr[1][1] + sdr[1][2] + sdr[1][3];
        sumf[0] = s0;
        sumf[1] = s1;
    }
    if (tid >= 64 && tid < 128) {   // wave 1: cross-ratio of raw x rows 0..3
        int l = tid - 64;
        const int pa[4] = {0, 1, 0, 1};
        const int pb[4] = {2, 3, 3, 2};
        double inner[4];
        for (int p = 0; p < 4; p++) {
            const float* a = x + pa[p] * 128;
            const float* b = x + pb[p] * 128;
            double s = (double)a[l] * (double)b[l];
            double t = (double)a[l + 64] * (double)b[l + 64];
            s += (l == 63) ? -t : t;
            for (int off = 32; off; off >>= 1) s += __shfl_xor(s, off);
            inner[p] = s;
        }
        if (l == 0) {
            double num = inner[0] * inner[1];
            double den = inner[2] * inner[3];
            if (fabs(den) < 1e-9) den = 1e-9;
            crin_sh = num / den;
        }
    }
    __syncthreads();
    int w = tid >> 6, o = tid & 63;
    float si0 = (float)(1.0 / sumf[0]);
    float si1 = (float)(1.0 / sumf[1]);
    const float* xr = xs + w * 128;
    const float* wr = Wo + (size_t)o * 128;
    float d0 = 0.f, d1 = 0.f;
    for (int j = 0; j < 64; j++) d0 = fmaf(xr[j], wr[j], d0);
    for (int j = 64; j < 128; j++) d1 = fmaf(xr[j], wr[j], d1);
    o4[w * 64 + o] = d0 * si0 + d1 * si1 + bo[o];
    __syncthreads();
    if (tid < 64) {
        int l = tid;
        const int pa[4] = {0, 1, 0, 1};
        const int pb[4] = {2, 3, 3, 2};
        double inner[4];
        for (int p = 0; p < 4; p++) {
            double t = (double)o4[pa[p] * 64 + l] * (double)o4[pb[p] * 64 + l];
            if (l == 63) t = -t;
            for (int off = 32; off; off >>= 1) t += __shfl_xor(t, off);
            inner[p] = t;
        }
        if (l == 0) {
            double num = inner[0] * inner[1];
            double den = inner[2] * inner[3];
            if (fabs(den) < 1e-9) den = 1e-9;
            double crc = num / den;
            if (fabs(crc) < 1e-9) crc = 1e-9;
            double ratio = crin_sh / crc;
            scalef[0] = (float)pow(fabs(ratio), 0.25);
        }
    }
}

// ---------------- final GEMM via split-fp16 MFMA: out = ((U/sumf)@Wo.T + bo)*scalef ----
__global__ void __launch_bounds__(256, 2)
k_outm(const float* __restrict__ U, const half8* __restrict__ wohi,
       const half8* __restrict__ wolo, const float* __restrict__ bo,
       const double* __restrict__ sumf, const float* __restrict__ scalef,
       float* __restrict__ out, int N) {
    __shared__ half8 bsh[2048];       // 32 KB: [0..1024) hi, [1024..2048) lo
    int tid = threadIdx.x;
    int wv = tid >> 6;                // wave 0..3
    int l = tid & 63;
    int r = l & 15;
    int g = l >> 4;
    int rowbase = blockIdx.x * 128 + wv * 32;

    {   // stage Wo frags
        const half8* sH = wohi + wv * 256;
        const half8* sL = wolo + wv * 256;
#pragma unroll
        for (int i = 0; i < 4; i++) {
            gl_lds16(sH + i * 64 + l, bsh + wv * 256 + i * 64);
            gl_lds16(sL + i * 64 + l, bsh + 1024 + wv * 256 + i * 64);
        }
    }

    float si0 = (float)(1.0 / sumf[0]);
    float si1 = (float)(1.0 / sumf[1]);
    const float4* U4 = (const float4*)U;
    half8 hiA[2][4], loA[2][4];
#pragma unroll
    for (int t = 0; t < 2; t++) {
        int row = min(rowbase + t * 16 + r, N - 1);
#pragma unroll
        for (int ks = 0; ks < 4; ks++) {
            float si = (ks < 2) ? si0 : si1;
            float4 a = U4[(size_t)row * 32 + ks * 8 + g * 2];
            float4 b = U4[(size_t)row * 32 + ks * 8 + g * 2 + 1];
            float xv[8] = {a.x, a.y, a.z, a.w, b.x, b.y, b.z, b.w};
#pragma unroll
            for (int j = 0; j < 8; j++) {
                float v = xv[j] * si;
                _Float16 hh = (_Float16)v;
                hiA[t][ks][j] = hh;
                loA[t][ks][j] = (_Float16)((v - (float)hh) * 4096.0f);
            }
        }
    }

    asm volatile("s_waitcnt vmcnt(0)" ::: "memory");
    __syncthreads();

    const f32x4 zz = {0.f, 0.f, 0.f, 0.f};
    f32x4 aM[2][4], aX[2][4];
#pragma unroll
    for (int t = 0; t < 2; t++)
#pragma unroll
        for (int ct = 0; ct < 4; ct++) { aM[t][ct] = zz; aX[t][ct] = zz; }

#pragma unroll
    for (int ks = 0; ks < 4; ks++) {
        half8 hB[4], lB[4];
#pragma unroll
        for (int ct = 0; ct < 4; ct++) {
            int bi = ks * 256 + g * 64 + ct * 16 + r;
            hB[ct] = bsh[bi];
            lB[ct] = bsh[1024 + bi];
        }
#pragma unroll
        for (int ct = 0; ct < 4; ct++) {
            aM[0][ct] = __builtin_amdgcn_mfma_f32_16x16x32_f16(hiA[0][ks], hB[ct], aM[0][ct], 0, 0, 0);
            aM[1][ct] = __builtin_amdgcn_mfma_f32_16x16x32_f16(hiA[1][ks], hB[ct], aM[1][ct], 0, 0, 0);
            aX[0][ct] = __builtin_amdgcn_mfma_f32_16x16x32_f16(hiA[0][ks], lB[ct], aX[0][ct], 0, 0, 0);
            aX[0][ct] = __builtin_amdgcn_mfma_f32_16x16x32_f16(loA[0][ks], hB[ct], aX[0][ct], 0, 0, 0);
            aX[1][ct] = __builtin_amdgcn_mfma_f32_16x16x32_f16(hiA[1][ks], lB[ct], aX[1][ct], 0, 0, 0);
            aX[1][ct] = __builtin_amdgcn_mfma_f32_16x16x32_f16(loA[1][ks], hB[ct], aX[1][ct], 0, 0, 0);
        }
    }

    float sf = scalef[0];
#pragma unroll
    for (int t = 0; t < 2; t++)
#pragma unroll
        for (int ct = 0; ct < 4; ct++) {
            float bb = bo[ct * 16 + r];
#pragma unroll
            for (int j = 0; j < 4; j++) {
                int row = rowbase + t * 16 + g * 4 + j;
                if (row < N) {
                    float c = (aM[t][ct][j] + aX[t][ct][j] * (1.0f / 4096.0f) + bb) * sf;
                    out[(size_t)row * 64 + ct * 16 + r] = c;
                }
            }
        }
}

extern "C" void kernel_launch(void* const* d_in, const int* in_sizes, int n_in,
                              void* d_out, int out_size, void* d_ws, size_t ws_size,
                              hipStream_t stream) {
    const float* x  = (const float*)d_in[0];
    const int*   ei = (const int*)d_in[1];
    const float* Wq = (const float*)d_in[2];
    const float* bq = (const float*)d_in[3];
    const float* Wk = (const float*)d_in[4];
    const float* bk = (const float*)d_in[5];
    const float* Wv = (const float*)d_in[6];
    const float* bv = (const float*)d_in[7];
    const float* Wo = (const float*)d_in[8];
    const float* bo = (const float*)d_in[9];
    float* out = (float*)d_out;

    const int N = in_sizes[0] / 128;   // 100000
    const int E = in_sizes[1] / 2;     // 1000000
    const size_t NR = (size_t)N * 128;
    const int NGB = (N + 127) / 128;   // 782 GEMM blocks (128 rows each)
    const int GB = (N + 7) / 8;        // 12500 edge-pass blocks
    const int chunk = (E + 255) / 256; // pass-1 sort chunk (256 chunks)
    const int NBINS = (N + 511) >> 9;  // 196 coarse bins (row>>9)

    float* qn = (float*)d_ws;          // N*128 f32 ; reused as U after edge passes
    float* vn = qn + NR;               // N*128 f32
    _Float16* knh = (_Float16*)(vn + NR);      // N*128 f16
    int* offs = (int*)(knh + NR);              // N+1
    int* ccol = offs + N + 2;                  // E (also packed tmp for the sort)
    int* bcnt = ccol + E;                      // 256*256
    int* bintot = bcnt + 256 * 256;            // 256
    int* binoff = bintot + 256;                // 257
    uintptr_t pe = ((uintptr_t)(binoff + 257 + 1) + 15) & ~(uintptr_t)15;
    float* e2 = (float*)pe;                    // 2*E per-head exp scores
    uintptr_t pd = ((uintptr_t)(e2 + 2 * (size_t)E) + 7) & ~(uintptr_t)7;
    double* psum = (double*)pd;                // GB*2 partial expsums
    double* sumf = psum + (size_t)GB * 2;      // 2
    float* scalef = (float*)(sumf + 2);        // 1

    // packed Wq/Wk/Wv frags alias ccol (dead until k_scat1, consumed by k_qkvm first)
    uintptr_t pw = ((uintptr_t)ccol + 15) & ~(uintptr_t)15;
    half8* whi = (half8*)pw;                   // 6144 * 16B
    half8* wlo = whi + 6144;                   // 6144 * 16B
    float* w127 = (float*)(wlo + 6144);        // 3*128 floats

    // packed Wo frags alias bcnt (dead after k_scat1; k_wpack2 runs after it)
    uintptr_t pw2 = ((uintptr_t)bcnt + 15) & ~(uintptr_t)15;
    half8* wohi = (half8*)pw2;                 // 1024 * 16B
    half8* wolo = wohi + 1024;                 // 1024 * 16B

    float* U = qn;  // aggregation output aliases q (q consumed by k_score)

    k_wpack<<<24, 256, 0, stream>>>(Wq, Wk, Wv, whi, wlo, w127);
    k_qkvm<<<NGB + 256, 256, 0, stream>>>(x, whi, wlo, w127, bq, bk, bv,
                                          qn, knh, vn, ei, bcnt, N, E, chunk);
    k_bin2<<<256, 256, 0, stream>>>(bcnt, bintot);
    k_bin3<<<1, 256, 0, stream>>>(bintot, binoff, offs, N, E);
    k_scat1<<<256, 256, 0, stream>>>(ei, bcnt, binoff, ccol, E, chunk);
    k_wpack2<<<4, 256, 0, stream>>>(Wo, wohi, wolo);   // bcnt space now dead
    k_sortf<<<NBINS, 256, 0, stream>>>(ccol, binoff, ccol, offs, N);
    k_score<<<GB, 256, 0, stream>>>(qn, knh, offs, ccol, e2, psum, N, E);
    k_aggr<<<GB, 256, 0, stream>>>(vn, offs, ccol, e2, U, N, E);
    k_crout4<<<1, 256, 0, stream>>>(x, U, Wo, bo, psum, GB, sumf, scalef);
    k_outm<<<NGB, 256, 0, stream>>>(U, wohi, wolo, bo, sumf, scalef, out, N);
}